// Round 1
// baseline (97.601 us; speedup 1.0000x reference)
//
#include <hip/hip_runtime.h>

// CIN fully fused, d-contraction-first. R9: phase 1 moved to
// v_mfma_f32_32x32x16_bf16 (k-pad 39->48 instead of 39->64; n=32 packs
// 2 batches x 16 d with zero n-waste; wA1 stream 624->468KB/block), plus
// 2-deep global prefetch in phases 1 and 3 to sit on the L2-stream floor.
//   out1[b,h] = sum_d h1[b,h,d];  h1 = sum_{f,q} W0[h,fq] x[b,f,d] x[b,q,d]
//   out2[b,h] = sum_p W1[h,p] U[b,p];  U[b,(f,q)] = sum_d x[b,f,d] h1[b,q,d]
// 256 blocks x 1024 thr (G=8 batch/block, 1 block/CU, ~140KB LDS).
//   phase 1: wave = (gp, mt); 3 chained 32x32x16 MFMAs per f, fp32 sx scale
//   phase 2b: wave = (g, qh); writes Ub2[f][g][q], imm-offset b16 stores
//   phase 3: wave = (t, kh); B-frags = b128 from Ub2, 2-cb-ahead W prefetch

#define F0   39
#define D_   16
#define H_   128
#define P0_  1521
#define P1_  4992
#define G8   8
#define NF1  (F0 * 3 * 4)   // 468 layer-1 A-frags (f x ks x mt), 32x32x16
#define NF2  (F0 * 4 * 8)   // 1248 W1 A-frags (16x16x32, unchanged)
#define SROW 136            // S_bf row stride in shorts (272B, 16B-aligned)
#define UGS  136            // Ub2 g-stride in shorts (272B: dw%32 = 4)
#define UFS  1096           // Ub2 f-stride in shorts (8*136+8; 2192B, 16B-aligned)

typedef __attribute__((ext_vector_type(8)))  short   short8;
typedef __attribute__((ext_vector_type(8)))  __bf16  bf16x8;
typedef __attribute__((ext_vector_type(4)))  float   floatx4;
typedef __attribute__((ext_vector_type(16))) float   floatx16;

__device__ __forceinline__ unsigned short bf16rne(float f) {
  unsigned int u = __float_as_uint(f);
  u += 0x7FFFu + ((u >> 16) & 1u);
  return (unsigned short)(u >> 16);
}

__device__ __forceinline__ floatx4 mfma16(short8 a, short8 b, floatx4 c) {
  return __builtin_amdgcn_mfma_f32_16x16x32_bf16(
      __builtin_bit_cast(bf16x8, a), __builtin_bit_cast(bf16x8, b), c, 0, 0, 0);
}

__device__ __forceinline__ floatx16 mfma32(short8 a, short8 b, floatx16 c) {
  return __builtin_amdgcn_mfma_f32_32x32x16_bf16(
      __builtin_bit_cast(bf16x8, a), __builtin_bit_cast(bf16x8, b), c, 0, 0, 0);
}

// ---------- pack W into MFMA A-frag order ----------
// wA1 (NEW, 32x32x16): frag = (f*3 + ks)*4 + mt
//   A[m][k]: m = mt*32 + (lane&31), k = (lane>>5)*8 + j, q = ks*16 + k
// wA2 (unchanged, 16x16x32): frag = (f*4 + s)*8 + t
__global__ __launch_bounds__(256) void pack_w_kernel(const float* __restrict__ w0,
                                                     const float* __restrict__ w1,
                                                     short8* __restrict__ wA1,
                                                     short8* __restrict__ wA2) {
  int id = blockIdx.x * 256 + threadIdx.x;
  union { short8 v; unsigned short e[8]; } pk;
  if (id < NF1 * 64) {
    int lane = id & 63, frag = id >> 6;
    int mt = frag & 3, fks = frag >> 2;
    int f = fks / 3, ks = fks - f * 3;
    int m = mt * 32 + (lane & 31);
    int q0 = ks * 16 + (lane >> 5) * 8;
#pragma unroll
    for (int j = 0; j < 8; ++j) {
      int q = q0 + j;
      pk.e[j] = (q < F0) ? bf16rne(w0[(size_t)m * P0_ + f * F0 + q]) : (unsigned short)0;
    }
    wA1[frag * 64 + lane] = pk.v;
  } else if (id < (NF1 + NF2) * 64) {
    int u = id - NF1 * 64;
    int lane = u & 63, frag = u >> 6;
    int t = frag & 7, s = (frag >> 3) & 3, f = frag >> 5;
    int m = t * 16 + (lane & 15);
    int pb = f * 128 + s * 32 + (lane >> 4) * 8;
#pragma unroll
    for (int j = 0; j < 8; ++j) pk.e[j] = bf16rne(w1[(size_t)m * P1_ + pb + j]);
    wA2[frag * 64 + lane] = pk.v;
  }
}

// ---------- fused main kernel ----------
__global__ __launch_bounds__(1024, 4) void cin_fused(const float* __restrict__ x,
                                                     const short8* __restrict__ wA1,
                                                     const short8* __restrict__ wA2,
                                                     float* __restrict__ out) {
  // LDS: [0,19968) xs fp32 (reused as S32 in phase-3 reduce)
  //      [19968, +34816) S_bf | [54784, +85488) xTb then Ub2 (aliased)
  __shared__ __align__(16) char smem[19968 + 128 * SROW * 2 + F0 * UFS * 2];
  float (*xs)[F0][D_]   = (float (*)[F0][D_])smem;
  float* S32            = (float*)smem;                               // phase 3 only
  unsigned short* S_bf  = (unsigned short*)(smem + 19968);            // [128][SROW]
  unsigned short* xTb   = (unsigned short*)(smem + 19968 + 128 * SROW * 2);
  unsigned short* Ub2   = xTb;                                        // aliased

  const int tid  = threadIdx.x;
  const int lane = tid & 63;
  const int wv   = tid >> 6;      // 16 waves
  const int col  = lane & 15;
  const int quad = lane >> 4;
  const int b0   = blockIdx.x * G8;
  const floatx4 zf4 = {0.f, 0.f, 0.f, 0.f};

  // ---- stage x (coalesced float4) ----
  {
    const float4* xg = (const float4*)(x + (size_t)b0 * (F0 * D_));
    float4* xl = (float4*)smem;
    for (int i = tid; i < G8 * F0 * D_ / 4; i += 1024) xl[i] = xg[i];
  }
  __syncthreads();

  // ---- xTb[g][q8][d][j] = bf16(x[g][q8*8+j][d]), zero-pad q>=39 ----
  if (tid < G8 * 8 * D_) {
    int i = tid;
    int d = i & 15, q8 = (i >> 4) & 7, g = i >> 7;
    union { short8 v; unsigned short e[8]; } pk;
#pragma unroll
    for (int j = 0; j < 8; ++j) {
      int q = q8 * 8 + j;
      pk.e[j] = (q < F0) ? bf16rne(xs[g][q][d]) : (unsigned short)0;
    }
    *(short8*)&xTb[(size_t)i * 8] = pk.v;
  }
  __syncthreads();

  // ===== phase 1: 32x32x16; wave = (gp, mt). C[m=h32][n=(g_lo,d)] =====
  //   per f: acf = sum_{q<48} W0[h, f*39+q] * x[g,q,d]; acc += acf * x[g,f,d]
  {
    const int mt  = wv & 3;          // h-tile of 32
    const int gp  = wv >> 2;         // batch pair: g = gp*2 + (c32>>4)
    const int c32 = lane & 31;       // C col: n = g_local*16 + d
    const int kg  = lane >> 5;       // k half (8 q's each)
    const int g   = gp * 2 + (c32 >> 4);
    const int d   = c32 & 15;

    // B[n][k]: n = c32, k = kg*8+j, q = ks*16 + k  ->  xTb[g][ks*2+kg][d][j]
    short8 bq0 = *(const short8*)&xTb[(size_t)(((g * 8 + 0 + kg) * 16) + d) * 8];
    short8 bq1 = *(const short8*)&xTb[(size_t)(((g * 8 + 2 + kg) * 16) + d) * 8];
    short8 bq2 = *(const short8*)&xTb[(size_t)(((g * 8 + 4 + kg) * 16) + d) * 8];

    floatx16 acc = {0.f, 0.f, 0.f, 0.f, 0.f, 0.f, 0.f, 0.f,
                    0.f, 0.f, 0.f, 0.f, 0.f, 0.f, 0.f, 0.f};
    const floatx16 zf16 = acc;

    // 2-f-ahead A prefetch
    short8 a0 = wA1[(size_t)(0 * 4 + mt) * 64 + lane];
    short8 a1 = wA1[(size_t)(1 * 4 + mt) * 64 + lane];
    short8 a2 = wA1[(size_t)(2 * 4 + mt) * 64 + lane];
    short8 b0f = wA1[(size_t)(3 * 4 + mt) * 64 + lane];
    short8 b1f = wA1[(size_t)(4 * 4 + mt) * 64 + lane];
    short8 b2f = wA1[(size_t)(5 * 4 + mt) * 64 + lane];
    for (int f = 0; f < F0; ++f) {
      const int f2 = (f + 2 < F0) ? f + 2 : F0 - 1;
      short8 n0 = wA1[(size_t)((f2 * 3 + 0) * 4 + mt) * 64 + lane];
      short8 n1 = wA1[(size_t)((f2 * 3 + 1) * 4 + mt) * 64 + lane];
      short8 n2 = wA1[(size_t)((f2 * 3 + 2) * 4 + mt) * 64 + lane];
      floatx16 acf = mfma32(a0, bq0, zf16);
      acf = mfma32(a1, bq1, acf);
      acf = mfma32(a2, bq2, acf);
      const float sx = xs[g][f][d];
      acc += acf * sx;
      a0 = b0f; a1 = b1f; a2 = b2f;
      b0f = n0; b1f = n1; b2f = n2;
    }
    // h1 -> S_bf (bf16). Row = h = mt*32 + ((r&3)+8*(r>>2)+4*kg), col = g*16+d.
    // dw-bank check: 16 consecutive dw per lane-half, halves offset by 16 banks.
#pragma unroll
    for (int r = 0; r < 16; ++r) {
      const int row = (r & 3) + 8 * (r >> 2) + 4 * kg;
      S_bf[(size_t)(mt * 32 + row) * SROW + gp * 32 + c32] = bf16rne(acc[r]);
    }
  }
  __syncthreads();

  // ===== phase 2a: out1[b,h] = sum_d h1 (1024 threads, one shot) =====
  {
    int h = tid & 127, g = tid >> 7;
    union { short8 v; unsigned int u[4]; } w0v, w1v;
    w0v.v = *(const short8*)&S_bf[(size_t)h * SROW + g * 16];
    w1v.v = *(const short8*)&S_bf[(size_t)h * SROW + g * 16 + 8];
    float sum = 0.f;
#pragma unroll
    for (int p = 0; p < 4; ++p) {
      sum += __uint_as_float(w0v.u[p] << 16) + __uint_as_float(w0v.u[p] & 0xFFFF0000u);
      sum += __uint_as_float(w1v.u[p] << 16) + __uint_as_float(w1v.u[p] & 0xFFFF0000u);
    }
    out[(size_t)(b0 + g) * 256 + h] = sum;
  }

  // ===== phase 2b: wave = (g, qh). U[g,(f,q)] = sum_d x[g,f,d] h1[g,q,d] =====
  // MFMA: A[m=f][k=d], B[n=q][k=d] -> C[m=f][n=q].
  // Store to Ub2[f][g][q]: imm-offset b16 stores, <=2-way banks.
  {
    const int g  = wv & 7;
    const int qh = wv >> 3;
    short8 af[3];
#pragma unroll
    for (int ft = 0; ft < 3; ++ft) {
      union { short8 v; unsigned short e[8]; } pk;
      int f = ft * 16 + col;
      if (quad < 2 && f < F0) {
        const float* xp = &xs[g][f][quad * 8];
#pragma unroll
        for (int j = 0; j < 8; ++j) pk.e[j] = bf16rne(xp[j]);
      } else {
#pragma unroll
        for (int j = 0; j < 8; ++j) pk.e[j] = 0;
      }
      af[ft] = pk.v;
    }
#pragma unroll
    for (int qi = 0; qi < 4; ++qi) {
      const int qt = qh * 4 + qi;
      short8 bq;
      if (quad < 2) {
        bq = *(const short8*)&S_bf[(size_t)(qt * 16 + col) * SROW + g * 16 + quad * 8];
      } else {
        bq = short8{0, 0, 0, 0, 0, 0, 0, 0};
      }
#pragma unroll
      for (int ft = 0; ft < 3; ++ft) {
        floatx4 c2 = mfma16(af[ft], bq, zf4);
        unsigned short* up =
            &Ub2[(size_t)(ft * 16 + quad * 4) * UFS + g * UGS + qt * 16 + col];
        if (ft < 2) {
#pragma unroll
          for (int r = 0; r < 4; ++r) up[r * UFS] = bf16rne(c2[r]);
        } else {
#pragma unroll
          for (int r = 0; r < 4; ++r)
            if (32 + quad * 4 + r < F0) up[r * UFS] = bf16rne(c2[r]);
        }
      }
    }
  }
  __syncthreads();

  // ===== phase 3: wave = (t, kh). out2 = sum_c W1frag(c) x Ufrag(c) =====
  // B-frag: k = quad*8+j over p = cb*128 + i*32 + k -> Ub2[cb][g=col][i*32+quad*8..+8]
  // W-frag prefetch 2 cb ahead: ~128KB/CU in flight to cover L2 latency.
  {
    const int t   = wv & 7;
    const int kh  = wv >> 3;
    const int cb0 = kh ? 20 : 0;
    const int cbN = kh ? F0 : 20;
    const short8 zero8 = {0, 0, 0, 0, 0, 0, 0, 0};
    floatx4 aco[4];
#pragma unroll
    for (int i = 0; i < 4; ++i) aco[i] = zf4;
    short8 aW[4], aX[4];
#pragma unroll
    for (int i = 0; i < 4; ++i)
      aW[i] = wA2[(size_t)((cb0 * 4 + i) * 8 + t) * 64 + lane];
#pragma unroll
    for (int i = 0; i < 4; ++i)
      aX[i] = wA2[(size_t)(((cb0 + 1) * 4 + i) * 8 + t) * 64 + lane];
    for (int cb = cb0; cb < cbN; ++cb) {
      const int c2 = (cb + 2 < cbN) ? cb + 2 : cbN - 1;
      short8 nx[4];
#pragma unroll
      for (int i = 0; i < 4; ++i)
        nx[i] = wA2[(size_t)((c2 * 4 + i) * 8 + t) * 64 + lane];
      const unsigned short* ubase = &Ub2[(size_t)cb * UFS + col * UGS + quad * 8];
#pragma unroll
      for (int i = 0; i < 4; ++i) {
        short8 bU = (col < 8) ? *(const short8*)(ubase + i * 32) : zero8;
        aco[i] = mfma16(aW[i], bU, aco[i]);
      }
#pragma unroll
      for (int i = 0; i < 4; ++i) { aW[i] = aX[i]; aX[i] = nx[i]; }
    }
    float v[4];
#pragma unroll
    for (int r = 0; r < 4; ++r)
      v[r] = (aco[0][r] + aco[1][r]) + (aco[2][r] + aco[3][r]);

    // k-half reduction through S32 (xs dead; stride 9 -> <=2-way banks)
    if (kh == 0 && col < 8) {
#pragma unroll
      for (int r = 0; r < 4; ++r)
        S32[(size_t)(t * 16 + quad * 4 + r) * 9 + col] = v[r];
    }
    __syncthreads();
    if (kh == 1 && col < 8) {
#pragma unroll
      for (int r = 0; r < 4; ++r) {
        int h = t * 16 + quad * 4 + r;
        out[(size_t)(b0 + col) * 256 + 128 + h] = v[r] + S32[(size_t)h * 9 + col];
      }
    }
  }
}

// ---------- fp32 last-resort fallback ----------
__global__ __launch_bounds__(128) void cin_fused_fallback(const float* __restrict__ x,
                                                          const float* __restrict__ w0,
                                                          const float* __restrict__ w1,
                                                          float* __restrict__ out) {
  __shared__ float4 xs4[F0 * D_ / 4];
  __shared__ float4 h1s4[H_ * D_ / 4];
  __shared__ float4 z4[H_ * D_ / 4];
  const int tid = threadIdx.x;
  const int b = blockIdx.x;
  const int hh = tid >> 2, dd = tid & 3, h0 = hh << 2;
  {
    const float4* xg = (const float4*)(x + (size_t)b * (F0 * D_));
    for (int i = tid; i < F0 * D_ / 4; i += 128) xs4[i] = xg[i];
  }
  __syncthreads();
  float acc[4][4];
#pragma unroll
  for (int i = 0; i < 4; ++i)
#pragma unroll
    for (int j = 0; j < 4; ++j) acc[i][j] = 0.f;
  for (int f = 0; f < F0; ++f) {
    for (int i = tid; i < F0 * D_ / 4; i += 128) {
      float4 xv = xs4[(f << 2) + (i & 3)], qv = xs4[i];
      z4[i] = make_float4(xv.x * qv.x, xv.y * qv.y, xv.z * qv.z, xv.w * qv.w);
    }
    __syncthreads();
    for (int q = 0; q < F0; ++q) {
      float4 zv = z4[(q << 2) + dd];
      int p = f * F0 + q;
      float ww[4] = {w0[(h0 + 0) * P0_ + p], w0[(h0 + 1) * P0_ + p],
                     w0[(h0 + 2) * P0_ + p], w0[(h0 + 3) * P0_ + p]};
      float zz[4] = {zv.x, zv.y, zv.z, zv.w};
#pragma unroll
      for (int hi = 0; hi < 4; ++hi)
#pragma unroll
        for (int di = 0; di < 4; ++di) acc[hi][di] += ww[hi] * zz[di];
    }
    __syncthreads();
  }
#pragma unroll
  for (int hi = 0; hi < 4; ++hi)
    h1s4[(h0 + hi) * 4 + dd] = make_float4(acc[hi][0], acc[hi][1], acc[hi][2], acc[hi][3]);
  __syncthreads();
  {
    float4 a0 = h1s4[tid * 4 + 0], a1 = h1s4[tid * 4 + 1];
    float4 a2 = h1s4[tid * 4 + 2], a3 = h1s4[tid * 4 + 3];
    out[(size_t)b * 256 + tid] = (a0.x + a0.y + a0.z + a0.w) + (a1.x + a1.y + a1.z + a1.w) +
                                 (a2.x + a2.y + a2.z + a2.w) + (a3.x + a3.y + a3.z + a3.w);
  }
#pragma unroll
  for (int i = 0; i < 4; ++i)
#pragma unroll
    for (int j = 0; j < 4; ++j) acc[i][j] = 0.f;
  for (int f = 0; f < F0; ++f) {
    for (int i = tid; i < H_ * D_ / 4; i += 128) {
      float4 xv = xs4[(f << 2) + (i & 3)], hv = h1s4[i];
      z4[i] = make_float4(xv.x * hv.x, xv.y * hv.y, xv.z * hv.z, xv.w * hv.w);
    }
    __syncthreads();
    for (int q = 0; q < H_; ++q) {
      float4 zv = z4[(q << 2) + dd];
      int p = f * H_ + q;
      float ww[4] = {w1[(h0 + 0) * P1_ + p], w1[(h0 + 1) * P1_ + p],
                     w1[(h0 + 2) * P1_ + p], w1[(h0 + 3) * P1_ + p]};
      float zz[4] = {zv.x, zv.y, zv.z, zv.w};
#pragma unroll
      for (int hi = 0; hi < 4; ++hi)
#pragma unroll
        for (int di = 0; di < 4; ++di) acc[hi][di] += ww[hi] * zz[di];
    }
    __syncthreads();
  }
#pragma unroll
  for (int hi = 0; hi < 4; ++hi)
    z4[(h0 + hi) * 4 + dd] = make_float4(acc[hi][0], acc[hi][1], acc[hi][2], acc[hi][3]);
  __syncthreads();
  {
    float4 a0 = z4[tid * 4 + 0], a1 = z4[tid * 4 + 1];
    float4 a2 = z4[tid * 4 + 2], a3 = z4[tid * 4 + 3];
    out[(size_t)b * 256 + 128 + tid] = (a0.x + a0.y + a0.z + a0.w) + (a1.x + a1.y + a1.z + a1.w) +
                                       (a2.x + a2.y + a2.z + a2.w) + (a3.x + a3.y + a3.z + a3.w);
  }
}

extern "C" void kernel_launch(void* const* d_in, const int* in_sizes, int n_in,
                              void* d_out, int out_size, void* d_ws, size_t ws_size,
                              hipStream_t stream) {
  const float* x  = (const float*)d_in[0];
  const float* w0 = (const float*)d_in[1];
  const float* w1 = (const float*)d_in[2];
  float* out = (float*)d_out;

  const size_t nfr    = (size_t)(NF1 + NF2) * 64;   // 109824 (frag,lane) pairs
  const size_t wbytes = nfr * sizeof(short8);       // ~1.76 MB

  if (ws_size >= wbytes) {
    short8* wA1 = (short8*)d_ws;
    short8* wA2 = wA1 + (size_t)NF1 * 64;
    pack_w_kernel<<<(int)((nfr + 255) / 256), 256, 0, stream>>>(w0, w1, wA1, wA2);
    cin_fused<<<256, 1024, 0, stream>>>(x, wA1, wA2, out);
  } else {
    cin_fused_fallback<<<2048, 128, 0, stream>>>(x, w0, w1, out);
  }
}